// Round 1
// baseline (2015.466 us; speedup 1.0000x reference)
//
#include <hip/hip_runtime.h>

#define T_STEPS 32
#define BB 4
#define DD 256
#define NN 1024
#define MM 256
#define KSH 3
#define RPL 265   // M+K+6
#define WPL 775   // 3M+K+4
#define EPSF 1e-12f

__device__ __forceinline__ float softplusf(float x){
    return fmaxf(x, 0.0f) + log1pf(expf(-fabsf(x)));
}
__device__ __forceinline__ float sigmoidf(float x){
    return 1.0f / (1.0f + expf(-x));
}

// ---- projections: rp = ctrl_t @ rW^T + rb ; wp = ctrl_t @ wW^T + wb ----
__global__ void kproj(const float* __restrict__ ctrl_t,
                      const float* __restrict__ rW, const float* __restrict__ rb,
                      const float* __restrict__ wW, const float* __restrict__ wb,
                      float* __restrict__ rp, float* __restrict__ wp){
    int o = blockIdx.x * blockDim.x + threadIdx.x;
    const int NR = BB * RPL;
    const int NW = BB * WPL;
    if (o >= NR + NW) return;
    const float* wrow; const float* crow; float bias; float* dst;
    if (o < NR){
        int b = o / RPL, j = o % RPL;
        wrow = rW + (size_t)j * DD; crow = ctrl_t + b * DD; bias = rb[j];
        dst = rp + b * RPL + j;
    } else {
        int oo = o - NR; int b = oo / WPL, j = oo % WPL;
        wrow = wW + (size_t)j * DD; crow = ctrl_t + b * DD; bias = wb[j];
        dst = wp + b * WPL + j;
    }
    const float4* c4 = (const float4*)crow;
    const float4* w4 = (const float4*)wrow;
    float acc = bias;
    #pragma unroll 8
    for (int d = 0; d < DD/4; d++){
        float4 a = c4[d], b_ = w4[d];
        acc += a.x*b_.x + a.y*b_.y + a.z*b_.z + a.w*b_.w;
    }
    *dst = acc;
}

// ---- cosine similarity: one wave per (b,n) row ----
__global__ void kcos(const float* __restrict__ mem, const float* __restrict__ params,
                     int plen, float* __restrict__ cosout){
    int gt = blockIdx.x * blockDim.x + threadIdx.x;
    int wv = gt >> 6, lane = gt & 63;
    if (wv >= BB * NN) return;
    int b = wv >> 10, n = wv & (NN - 1);
    const float4* mrow = (const float4*)(mem + ((size_t)(b * NN + n)) * MM);
    const float* key = params + (size_t)b * plen;   // key at offset 0 (may be unaligned for float4)
    float4 m4 = mrow[lane];
    float k0 = key[lane*4+0], k1 = key[lane*4+1], k2 = key[lane*4+2], k3 = key[lane*4+3];
    float dot = m4.x*k0 + m4.y*k1 + m4.z*k2 + m4.w*k3;
    float nm  = m4.x*m4.x + m4.y*m4.y + m4.z*m4.z + m4.w*m4.w;
    float nk  = k0*k0 + k1*k1 + k2*k2 + k3*k3;
    #pragma unroll
    for (int off = 32; off > 0; off >>= 1){
        dot += __shfl_down(dot, off);
        nm  += __shfl_down(nm , off);
        nk  += __shfl_down(nk , off);
    }
    if (lane == 0)
        cosout[b*NN + n] = dot / ((sqrtf(nm) + EPSF) * (sqrtf(nk) + EPSF));
}

// ---- write addressing: one block per batch, outputs new write_w (post a_gate) in place ----
__global__ void kaddr_w(const float* __restrict__ cosw, const float* __restrict__ wp,
                        float* __restrict__ write_w){
    int b = blockIdx.x, tid = threadIdx.x;
    __shared__ float sred[256];
    __shared__ float wg[NN];
    const float* p = wp + (size_t)b * WPL;
    float beta_p = softplusf(p[MM]);
    float g = sigmoidf(p[MM+1]);
    float s0r = p[MM+2], s1r = p[MM+3], s2r = p[MM+4];
    float smx = fmaxf(s0r, fmaxf(s1r, s2r));
    float e0 = expf(s0r-smx), e1 = expf(s1r-smx), e2 = expf(s2r-smx);
    float sden = e0+e1+e2;
    float s0 = e0/sden, s1 = e1/sden, s2 = e2/sden;
    float gamma_p = 1.0f + softplusf(p[MM+2+KSH]);
    float agate = sigmoidf(p[3*MM+3+KSH]);

    float x[4]; float lmax = -INFINITY;
    #pragma unroll
    for (int q = 0; q < 4; q++){ int i = tid + q*256; x[q] = beta_p * cosw[b*NN+i]; lmax = fmaxf(lmax, x[q]); }
    sred[tid] = lmax; __syncthreads();
    for (int s = 128; s > 0; s >>= 1){ if (tid < s) sred[tid] = fmaxf(sred[tid], sred[tid+s]); __syncthreads(); }
    float bmax = sred[0]; __syncthreads();
    float ev[4]; float lsum = 0.0f;
    #pragma unroll
    for (int q = 0; q < 4; q++){ ev[q] = expf(x[q]-bmax); lsum += ev[q]; }
    sred[tid] = lsum; __syncthreads();
    for (int s = 128; s > 0; s >>= 1){ if (tid < s) sred[tid] += sred[tid+s]; __syncthreads(); }
    float bsum = sred[0]; __syncthreads();
    #pragma unroll
    for (int q = 0; q < 4; q++){
        int i = tid + q*256;
        float wc = ev[q] / bsum;
        wg[i] = g*wc + (1.0f-g) * write_w[b*NN+i];
    }
    __syncthreads();
    float wt[4]; float lps = 0.0f;
    #pragma unroll
    for (int q = 0; q < 4; q++){
        int i = tid + q*256;
        float sh = s0*wg[(i+1)&(NN-1)] + s1*wg[i] + s2*wg[(i-1)&(NN-1)];
        wt[q] = powf(sh + EPSF, gamma_p); lps += wt[q];
    }
    sred[tid] = lps; __syncthreads();
    for (int s = 128; s > 0; s >>= 1){ if (tid < s) sred[tid] += sred[tid+s]; __syncthreads(); }
    float tsum = sred[0]; __syncthreads();
    float inv = 1.0f / (tsum + EPSF);
    #pragma unroll
    for (int q = 0; q < 4; q++){
        int i = tid + q*256;
        write_w[b*NN+i] = (1.0f - agate) * (wt[q] * inv);   // alloc == 0 exactly (cumprod starts at 0)
    }
}

// ---- memory update ----
__global__ void kmem(float* __restrict__ mem, const float* __restrict__ w_wr,
                     const float* __restrict__ wp){
    int idx = blockIdx.x * blockDim.x + threadIdx.x;  // 0 .. B*N*M/4-1
    int b = idx >> 16;
    int rem = idx & 65535;
    int n = rem >> 6;
    int m4 = (rem & 63) << 2;
    float w = w_wr[b*NN + n];
    const float* p = wp + (size_t)b * WPL;
    const float* pe = p + MM + 3 + KSH;       // erase raw
    const float* pa = p + 2*MM + 3 + KSH;     // add raw
    float4 mm = ((float4*)mem)[idx];
    float er0 = sigmoidf(pe[m4+0]), er1 = sigmoidf(pe[m4+1]), er2 = sigmoidf(pe[m4+2]), er3 = sigmoidf(pe[m4+3]);
    float ad0 = pa[m4+0], ad1 = pa[m4+1], ad2 = pa[m4+2], ad3 = pa[m4+3];
    mm.x = mm.x * (1.0f - w*er0) + w*ad0;
    mm.y = mm.y * (1.0f - w*er1) + w*ad1;
    mm.z = mm.z * (1.0f - w*er2) + w*ad2;
    mm.w = mm.w * (1.0f - w*er3) + w*ad3;
    ((float4*)mem)[idx] = mm;
}

// ---- link update fused with fwd/bwd partial matvecs (uses OLD prec, OLD read_w) ----
// grid: B*64 blocks (16 rows each), 256 threads (each owns 4 columns)
__global__ void klinkfb(const float* __restrict__ w_wr, const float* __restrict__ prec,
                        const float* __restrict__ read_w, float* __restrict__ link,
                        float* __restrict__ bwdv, float* __restrict__ fwd_part){
    int blk = blockIdx.x;
    int b = blk >> 6, c = blk & 63;
    int tid = threadIdx.x;
    int j0 = tid * 4;
    __shared__ float sred[4];
    float4 wj = *(const float4*)(w_wr + b*NN + j0);
    float4 rj = *(const float4*)(read_w + b*NN + j0);
    float4 pf = make_float4(0.f, 0.f, 0.f, 0.f);
    float* Lb = link + (size_t)b * NN * NN;
    for (int ii = 0; ii < 16; ii++){
        int i = c*16 + ii;
        float wi = w_wr[b*NN + i];
        float pr = prec[b*NN + i];
        float ri = read_w[b*NN + i];
        float om = 1.0f - wi;
        float4 L4 = *(float4*)(Lb + (size_t)i*NN + j0);
        float4 Ln;
        Ln.x = om*L4.x + pr*wj.x;
        Ln.y = om*L4.y + pr*wj.y;
        Ln.z = om*L4.z + pr*wj.z;
        Ln.w = om*L4.w + pr*wj.w;
        if (i >= j0 && i < j0+4){           // zero diagonal
            if (i == j0  ) Ln.x = 0.f;
            if (i == j0+1) Ln.y = 0.f;
            if (i == j0+2) Ln.z = 0.f;
            if (i == j0+3) Ln.w = 0.f;
        }
        *(float4*)(Lb + (size_t)i*NN + j0) = Ln;
        // bwd[i] = sum_j Ln[i,j]*r[j]  (block reduce)
        float br = Ln.x*rj.x + Ln.y*rj.y + Ln.z*rj.z + Ln.w*rj.w;
        #pragma unroll
        for (int off = 32; off > 0; off >>= 1) br += __shfl_down(br, off);
        if ((tid & 63) == 0) sred[tid >> 6] = br;
        __syncthreads();
        if (tid == 0) bwdv[b*NN + i] = sred[0] + sred[1] + sred[2] + sred[3];
        __syncthreads();
        // fwd partial: pf[j] += r[i]*Ln[i,j]
        pf.x += ri * Ln.x;
        pf.y += ri * Ln.y;
        pf.z += ri * Ln.z;
        pf.w += ri * Ln.w;
    }
    *(float4*)(fwd_part + ((size_t)(b*64 + c))*NN + j0) = pf;
}

// ---- read addressing + pi mix + prec update: one block per batch ----
__global__ void kaddr_r(const float* __restrict__ cosr, const float* __restrict__ rp,
                        const float* __restrict__ bwdv, const float* __restrict__ fwd_part,
                        const float* __restrict__ w_wr, float* __restrict__ prec,
                        float* __restrict__ read_w){
    int b = blockIdx.x, tid = threadIdx.x;
    __shared__ float sred[256];
    __shared__ float wg[NN];
    const float* p = rp + (size_t)b * RPL;
    float beta_p = softplusf(p[MM]);
    float g = sigmoidf(p[MM+1]);
    float s0r = p[MM+2], s1r = p[MM+3], s2r = p[MM+4];
    float smx = fmaxf(s0r, fmaxf(s1r, s2r));
    float e0 = expf(s0r-smx), e1 = expf(s1r-smx), e2 = expf(s2r-smx);
    float sden = e0+e1+e2;
    float s0 = e0/sden, s1 = e1/sden, s2 = e2/sden;
    float gamma_p = 1.0f + softplusf(p[MM+2+KSH]);
    float pr0 = p[MM+3+KSH], pr1 = p[MM+4+KSH], pr2 = p[MM+5+KSH];
    float pmx = fmaxf(pr0, fmaxf(pr1, pr2));
    float q0 = expf(pr0-pmx), q1 = expf(pr1-pmx), q2 = expf(pr2-pmx);
    float qs = q0+q1+q2;
    float pi0 = q0/qs, pi1 = q1/qs, pi2 = q2/qs;

    float x[4]; float lmax = -INFINITY;
    #pragma unroll
    for (int q = 0; q < 4; q++){ int i = tid + q*256; x[q] = beta_p * cosr[b*NN+i]; lmax = fmaxf(lmax, x[q]); }
    sred[tid] = lmax; __syncthreads();
    for (int s = 128; s > 0; s >>= 1){ if (tid < s) sred[tid] = fmaxf(sred[tid], sred[tid+s]); __syncthreads(); }
    float bmax = sred[0]; __syncthreads();
    float ev[4]; float lsum = 0.0f;
    #pragma unroll
    for (int q = 0; q < 4; q++){ ev[q] = expf(x[q]-bmax); lsum += ev[q]; }
    sred[tid] = lsum; __syncthreads();
    for (int s = 128; s > 0; s >>= 1){ if (tid < s) sred[tid] += sred[tid+s]; __syncthreads(); }
    float bsum = sred[0]; __syncthreads();
    #pragma unroll
    for (int q = 0; q < 4; q++){
        int i = tid + q*256;
        float wc = ev[q] / bsum;
        wg[i] = g*wc + (1.0f-g) * read_w[b*NN+i];
    }
    __syncthreads();
    float wt[4]; float lps = 0.0f;
    #pragma unroll
    for (int q = 0; q < 4; q++){
        int i = tid + q*256;
        float sh = s0*wg[(i+1)&(NN-1)] + s1*wg[i] + s2*wg[(i-1)&(NN-1)];
        wt[q] = powf(sh + EPSF, gamma_p); lps += wt[q];
    }
    sred[tid] = lps; __syncthreads();
    for (int s = 128; s > 0; s >>= 1){ if (tid < s) sred[tid] += sred[tid+s]; __syncthreads(); }
    float tsum = sred[0]; __syncthreads();
    float inv = 1.0f / (tsum + EPSF);
    #pragma unroll
    for (int q = 0; q < 4; q++){
        int i = tid + q*256;
        float wc_final = wt[q] * inv;
        float fwd = 0.0f;
        for (int ch = 0; ch < 64; ch++)
            fwd += fwd_part[((size_t)(b*64 + ch))*NN + i];
        float wnew = pi0 * bwdv[b*NN+i] + pi1 * wc_final + pi2 * fwd;
        read_w[b*NN+i] = wnew;
        // prec update: sum over BATCH axis (matches reference's w.sum(axis=0))
        float wsum = w_wr[0*NN+i] + w_wr[1*NN+i] + w_wr[2*NN+i] + w_wr[3*NN+i];
        prec[b*NN+i] = (1.0f - wsum) * prec[b*NN+i] + w_wr[b*NN+i];
    }
}

// ---- reads = read_w @ memory : partials over n-chunks, then reduce ----
__global__ void kread_part(const float* __restrict__ mem, const float* __restrict__ read_w,
                           float* __restrict__ part){
    int b = blockIdx.x >> 4, cck = blockIdx.x & 15;
    int m = threadIdx.x;
    float acc = 0.0f;
    int n0 = cck * 64;
    for (int n = n0; n < n0 + 64; n++)
        acc += read_w[b*NN + n] * mem[((size_t)(b*NN + n))*MM + m];
    part[(b*16 + cck)*MM + m] = acc;
}

__global__ void kread_red(const float* __restrict__ part, float* __restrict__ out_t){
    int b = blockIdx.x;
    int m = threadIdx.x;
    float acc = 0.0f;
    #pragma unroll
    for (int cck = 0; cck < 16; cck++)
        acc += part[(b*16 + cck)*MM + m];
    out_t[b*MM + m] = acc;   // RH == 1
}

extern "C" void kernel_launch(void* const* d_in, const int* in_sizes, int n_in,
                              void* d_out, int out_size, void* d_ws, size_t ws_size,
                              hipStream_t stream) {
    const float* ctrl   = (const float*)d_in[0];
    const float* read_W = (const float*)d_in[1];
    const float* read_b = (const float*)d_in[2];
    const float* write_W= (const float*)d_in[3];
    const float* write_b= (const float*)d_in[4];
    const float* memory0= (const float*)d_in[5];
    const float* link0  = (const float*)d_in[6];
    const float* prec0  = (const float*)d_in[7];
    // d_in[8] = usage0: provably dead (allocation weights are identically zero)
    const float* read_w0 = (const float*)d_in[9];
    const float* write_w0= (const float*)d_in[10];
    float* out = (float*)d_out;

    float* ws = (float*)d_ws;
    const size_t MEM_F  = (size_t)BB*NN*MM;   // 1048576
    const size_t LINK_F = (size_t)BB*NN*NN;   // 4194304
    float* mem     = ws;                    // 1048576
    float* link    = mem + MEM_F;           // 4194304
    float* prec    = link + LINK_F;         // 4096
    float* read_w  = prec + BB*NN;          // 4096
    float* write_w = read_w + BB*NN;        // 4096
    float* rp      = write_w + BB*NN;       // pad to 1072
    float* wp      = rp + 1072;             // pad to 3104
    float* cosw    = wp + 3104;             // 4096
    float* cosr    = cosw + BB*NN;          // 4096
    float* bwdv    = cosr + BB*NN;          // 4096
    float* fwd_part= bwdv + BB*NN;          // B*64*N = 262144
    float* rpart   = fwd_part + (size_t)BB*64*NN;  // B*16*M = 16384

    hipMemcpyAsync(mem,     memory0,  MEM_F  * sizeof(float), hipMemcpyDeviceToDevice, stream);
    hipMemcpyAsync(link,    link0,    LINK_F * sizeof(float), hipMemcpyDeviceToDevice, stream);
    hipMemcpyAsync(prec,    prec0,    (size_t)BB*NN * sizeof(float), hipMemcpyDeviceToDevice, stream);
    hipMemcpyAsync(read_w,  read_w0,  (size_t)BB*NN * sizeof(float), hipMemcpyDeviceToDevice, stream);
    hipMemcpyAsync(write_w, write_w0, (size_t)BB*NN * sizeof(float), hipMemcpyDeviceToDevice, stream);

    const int projGrid = (BB*(RPL+WPL) + 255) / 256;
    for (int t = 0; t < T_STEPS; t++){
        const float* ctrl_t = ctrl + (size_t)t*BB*DD;
        kproj<<<projGrid, 256, 0, stream>>>(ctrl_t, read_W, read_b, write_W, write_b, rp, wp);
        kcos<<<(BB*NN*64)/256, 256, 0, stream>>>(mem, wp, WPL, cosw);
        kaddr_w<<<BB, 256, 0, stream>>>(cosw, wp, write_w);
        kmem<<<(BB*NN*MM/4)/256, 256, 0, stream>>>(mem, write_w, wp);
        klinkfb<<<BB*64, 256, 0, stream>>>(write_w, prec, read_w, link, bwdv, fwd_part);
        kcos<<<(BB*NN*64)/256, 256, 0, stream>>>(mem, rp, RPL, cosr);
        kaddr_r<<<BB, 256, 0, stream>>>(cosr, rp, bwdv, fwd_part, write_w, prec, read_w);
        kread_part<<<BB*16, 256, 0, stream>>>(mem, read_w, rpart);
        kread_red<<<BB, 256, 0, stream>>>(rpart, out + (size_t)t*BB*MM);
    }
}

// Round 2
// 869.820 us; speedup vs baseline: 2.3171x; 2.3171x over previous
//
#include <hip/hip_runtime.h>

#define T_STEPS 32
#define BB 4
#define DD 256
#define NN 1024
#define MM 256
#define KSH 3
#define RPL 265   // M+K+6
#define WPL 775   // 3M+K+4
#define EPSF 1e-12f

__device__ __forceinline__ float softplusf(float x){
    return fmaxf(x, 0.0f) + log1pf(expf(-fabsf(x)));
}
__device__ __forceinline__ float sigmoidf(float x){
    return 1.0f / (1.0f + expf(-x));
}

// ---- block reduce helpers: wave shfl + 4-slot LDS, 2 barriers each ----
__device__ __forceinline__ float blk_sum(float v, float* s4, int tid){
    #pragma unroll
    for (int off = 32; off > 0; off >>= 1) v += __shfl_down(v, off);
    if ((tid & 63) == 0) s4[tid >> 6] = v;
    __syncthreads();
    float r = s4[0] + s4[1] + s4[2] + s4[3];
    __syncthreads();
    return r;
}
__device__ __forceinline__ float blk_max(float v, float* s4, int tid){
    #pragma unroll
    for (int off = 32; off > 0; off >>= 1) v = fmaxf(v, __shfl_down(v, off));
    if ((tid & 63) == 0) s4[tid >> 6] = v;
    __syncthreads();
    float r = fmaxf(fmaxf(s4[0], s4[1]), fmaxf(s4[2], s4[3]));
    __syncthreads();
    return r;
}

// ---- shared addressing core (content softmax -> gate -> shift -> sharpen) ----
// cosv: cos values for this batch (N). prev[4]: previous weights at i=tid+q*256.
// p: param row (beta at [M], gate [M+1], shift [M+2..M+4], gamma [M+2+K]).
// out_wc[q]: normalized sharpened weights.
__device__ __forceinline__ void addr_core(const float* __restrict__ cosv,
                                          const float prev[4],
                                          const float* __restrict__ p,
                                          float* s4, float* wg, int tid,
                                          float out_wc[4]){
    float beta_p  = softplusf(p[MM]);
    float g       = sigmoidf(p[MM+1]);
    float s0r = p[MM+2], s1r = p[MM+3], s2r = p[MM+4];
    float smx = fmaxf(s0r, fmaxf(s1r, s2r));
    float e0 = expf(s0r-smx), e1 = expf(s1r-smx), e2 = expf(s2r-smx);
    float sden = e0+e1+e2;
    float s0 = e0/sden, s1 = e1/sden, s2 = e2/sden;
    float gamma_p = 1.0f + softplusf(p[MM+2+KSH]);

    float x[4]; float lmax = -INFINITY;
    #pragma unroll
    for (int q = 0; q < 4; q++){ x[q] = beta_p * cosv[tid + q*256]; lmax = fmaxf(lmax, x[q]); }
    float bmax = blk_max(lmax, s4, tid);
    float ev[4]; float ls = 0.0f;
    #pragma unroll
    for (int q = 0; q < 4; q++){ ev[q] = expf(x[q]-bmax); ls += ev[q]; }
    float bs = blk_sum(ls, s4, tid);
    float invb = 1.0f / bs;
    #pragma unroll
    for (int q = 0; q < 4; q++){
        int i = tid + q*256;
        wg[i] = g*(ev[q]*invb) + (1.0f-g)*prev[q];
    }
    __syncthreads();
    float wt[4]; float lps = 0.0f;
    #pragma unroll
    for (int q = 0; q < 4; q++){
        int i = tid + q*256;
        float sh = s0*wg[(i+1)&(NN-1)] + s1*wg[i] + s2*wg[(i-1)&(NN-1)];
        wt[q] = powf(sh + EPSF, gamma_p);
        lps += wt[q];
    }
    float ts = blk_sum(lps, s4, tid);
    float inv = 1.0f / (ts + EPSF);
    #pragma unroll
    for (int q = 0; q < 4; q++) out_wc[q] = wt[q] * inv;
    __syncthreads();   // protect wg for possible reuse
}

// ---- all projections for all 32 steps, one shot. Erase slice pre-sigmoided. ----
// grid: 32 t * 8 j-chunks = 256 blocks, 256 threads (130 active)
__global__ void kproj_all(const float* __restrict__ ctrl,
                          const float* __restrict__ rW, const float* __restrict__ rb,
                          const float* __restrict__ wW, const float* __restrict__ wb,
                          float* __restrict__ rp, float* __restrict__ wp){
    int t  = blockIdx.x >> 3;
    int jc = blockIdx.x & 7;
    int tid = threadIdx.x;
    __shared__ float lc[BB*DD];
    for (int o = tid; o < BB*DD; o += 256) lc[o] = ctrl[(size_t)t*BB*DD + o];
    __syncthreads();
    int j = jc*130 + tid;
    if (tid >= 130 || j >= RPL + WPL) return;
    const float* wrow; float bias; int isw, jj;
    if (j < RPL){ jj = j;        wrow = rW + (size_t)jj*DD; bias = rb[jj]; isw = 0; }
    else        { jj = j - RPL;  wrow = wW + (size_t)jj*DD; bias = wb[jj]; isw = 1; }
    const float4* w4 = (const float4*)wrow;
    float a0 = bias, a1 = bias, a2 = bias, a3 = bias;
    for (int d = 0; d < DD/4; d++){
        float4 wv = w4[d];
        float4 c0 = *(const float4*)&lc[0*DD + d*4];
        float4 c1 = *(const float4*)&lc[1*DD + d*4];
        float4 c2 = *(const float4*)&lc[2*DD + d*4];
        float4 c3 = *(const float4*)&lc[3*DD + d*4];
        a0 += wv.x*c0.x + wv.y*c0.y + wv.z*c0.z + wv.w*c0.w;
        a1 += wv.x*c1.x + wv.y*c1.y + wv.z*c1.z + wv.w*c1.w;
        a2 += wv.x*c2.x + wv.y*c2.y + wv.z*c2.z + wv.w*c2.w;
        a3 += wv.x*c3.x + wv.y*c3.y + wv.z*c3.z + wv.w*c3.w;
    }
    if (isw && jj >= MM+3+KSH && jj < 2*MM+3+KSH){  // erase -> sigmoid here, once
        a0 = sigmoidf(a0); a1 = sigmoidf(a1); a2 = sigmoidf(a2); a3 = sigmoidf(a3);
    }
    if (!isw){
        float* dst = rp + (size_t)t*BB*RPL;
        dst[0*RPL+jj]=a0; dst[1*RPL+jj]=a1; dst[2*RPL+jj]=a2; dst[3*RPL+jj]=a3;
    } else {
        float* dst = wp + (size_t)t*BB*WPL;
        dst[0*WPL+jj]=a0; dst[1*WPL+jj]=a1; dst[2*WPL+jj]=a2; dst[3*WPL+jj]=a3;
    }
}

// ---- prologue: copy memory0 -> ws mem, cos(memory0, key_w^0), copy prec0/read_w0 ----
__global__ void kprep(const float* __restrict__ memory0, const float* __restrict__ wp0,
                      float* __restrict__ mem, float* __restrict__ cosw,
                      const float* __restrict__ prec0, const float* __restrict__ read_w0,
                      float* __restrict__ prec, float* __restrict__ read_w){
    int tid = threadIdx.x;
    int gid = blockIdx.x*256 + tid;
    if (gid < BB*NN){ prec[gid] = prec0[gid]; read_w[gid] = read_w0[gid]; }
    int wv = gid >> 6, lane = gid & 63;
    int b = wv >> 10, n = wv & (NN-1);
    size_t ridx = (size_t)(b*NN+n)*64 + lane;
    float4 m4 = ((const float4*)memory0)[ridx];
    ((float4*)mem)[ridx] = m4;
    const float* kw = wp0 + (size_t)b*WPL;
    int m0 = lane*4;
    float k0=kw[m0], k1=kw[m0+1], k2=kw[m0+2], k3=kw[m0+3];
    float dw = m4.x*k0 + m4.y*k1 + m4.z*k2 + m4.w*k3;
    float nm = m4.x*m4.x + m4.y*m4.y + m4.z*m4.z + m4.w*m4.w;
    float nk = k0*k0 + k1*k1 + k2*k2 + k3*k3;
    #pragma unroll
    for (int off = 32; off > 0; off >>= 1){
        dw += __shfl_down(dw, off);
        nm += __shfl_down(nm, off);
        nk += __shfl_down(nk, off);
    }
    if (lane == 0)
        cosw[b*NN+n] = dw / ((sqrtf(nm)+EPSF)*(sqrtf(nk)+EPSF));
}

// ---- write addressing for t=0 ----
__global__ void kaddr_w0(const float* __restrict__ cosw, const float* __restrict__ wp0,
                         const float* __restrict__ write_w0, float* __restrict__ wb0){
    int b = blockIdx.x, tid = threadIdx.x;
    __shared__ float s4[4];
    __shared__ float wg[NN];
    float prev[4];
    #pragma unroll
    for (int q = 0; q < 4; q++) prev[q] = write_w0[b*NN + tid + q*256];
    const float* p = wp0 + (size_t)b*WPL;
    float wcf[4];
    addr_core(cosw + b*NN, prev, p, s4, wg, tid, wcf);
    float ag = sigmoidf(p[3*MM+3+KSH]);
    #pragma unroll
    for (int q = 0; q < 4; q++)
        wb0[b*NN + tid + q*256] = (1.0f-ag)*wcf[q];   // alloc == 0 exactly
}

// ---- BIG: memory update + cos_r^t + cos_w^{t+1}, single pass over memory ----
__global__ void kmemcos(float* __restrict__ mem, const float* __restrict__ wbt,
                        const float* __restrict__ wp_t, const float* __restrict__ rp_t,
                        const float* __restrict__ wp_next,
                        float* __restrict__ cosr, float* __restrict__ cosw){
    int tid = threadIdx.x;
    int wv = blockIdx.x*4 + (tid>>6);
    int lane = tid & 63;
    int b = wv >> 10, n = wv & (NN-1);
    float w = wbt[b*NN+n];
    const float* pw = wp_t + (size_t)b*WPL;
    int m0 = lane*4;
    // erase pre-sigmoided in kproj_all
    float e0 = pw[MM+3+KSH+m0+0], e1 = pw[MM+3+KSH+m0+1];
    float e2 = pw[MM+3+KSH+m0+2], e3 = pw[MM+3+KSH+m0+3];
    float a0 = pw[2*MM+3+KSH+m0+0], a1 = pw[2*MM+3+KSH+m0+1];
    float a2 = pw[2*MM+3+KSH+m0+2], a3 = pw[2*MM+3+KSH+m0+3];
    size_t ridx = (size_t)(b*NN+n)*64 + lane;
    float4 m4 = ((const float4*)mem)[ridx];
    m4.x = m4.x*(1.0f - w*e0) + w*a0;
    m4.y = m4.y*(1.0f - w*e1) + w*a1;
    m4.z = m4.z*(1.0f - w*e2) + w*a2;
    m4.w = m4.w*(1.0f - w*e3) + w*a3;
    ((float4*)mem)[ridx] = m4;
    const float* kr = rp_t + (size_t)b*RPL;
    const float* kw = wp_next + (size_t)b*WPL;
    float r0=kr[m0], r1=kr[m0+1], r2=kr[m0+2], r3=kr[m0+3];
    float k0=kw[m0], k1=kw[m0+1], k2=kw[m0+2], k3=kw[m0+3];
    float dr = m4.x*r0 + m4.y*r1 + m4.z*r2 + m4.w*r3;
    float dw = m4.x*k0 + m4.y*k1 + m4.z*k2 + m4.w*k3;
    float nm = m4.x*m4.x + m4.y*m4.y + m4.z*m4.z + m4.w*m4.w;
    float nr = r0*r0 + r1*r1 + r2*r2 + r3*r3;
    float nk = k0*k0 + k1*k1 + k2*k2 + k3*k3;
    #pragma unroll
    for (int off = 32; off > 0; off >>= 1){
        dr += __shfl_down(dr, off); dw += __shfl_down(dw, off);
        nm += __shfl_down(nm, off); nr += __shfl_down(nr, off);
        nk += __shfl_down(nk, off);
    }
    if (lane == 0){
        float sn = sqrtf(nm) + EPSF;
        cosr[b*NN+n] = dr / (sn*(sqrtf(nr)+EPSF));
        cosw[b*NN+n] = dw / (sn*(sqrtf(nk)+EPSF));
    }
}

// ---- state kernel: link-factor update, fwd/bwd, prec, read addressing,
//      write addressing for t+1 (double-buffered write_w), zero out[t] ----
__global__ void kstate(int t, int do_next,
                       float* __restrict__ A, float* __restrict__ Wf,
                       float* __restrict__ prec, float* __restrict__ read_w,
                       const float* __restrict__ wbt, float* __restrict__ wbn,
                       const float* __restrict__ cosr, const float* __restrict__ cosw,
                       const float* __restrict__ rp_t, const float* __restrict__ wp_next,
                       float* __restrict__ out_t){
    int b = blockIdx.x, tid = threadIdx.x;
    __shared__ float s4[4];
    __shared__ float wg[NN];
    __shared__ float cs_l[T_STEPS], ds_l[T_STEPS];

    float wt_[4], ro_[4], po_[4];
    #pragma unroll
    for (int q = 0; q < 4; q++){
        int i = tid + q*256;
        wt_[q] = wbt[b*NN+i];
        ro_[q] = read_w[b*NN+i];
        po_[q] = prec[b*NN+i];
    }
    // link factor update: A_s *= (1-w_t) for s<t; append A_t = prec_{t-1}, W_t = w_t
    for (int s = 0; s < t; s++){
        size_t base = ((size_t)(b*T_STEPS + s))*NN;
        #pragma unroll
        for (int q = 0; q < 4; q++){
            int i = tid + q*256;
            A[base+i] *= (1.0f - wt_[q]);
        }
    }
    {
        size_t base = ((size_t)(b*T_STEPS + t))*NN;
        #pragma unroll
        for (int q = 0; q < 4; q++){
            int i = tid + q*256;
            A[base+i]  = po_[q];
            Wf[base+i] = wt_[q];
        }
    }
    __syncthreads();
    // c_s = r·A_s, d_s = r·W_s  (waves split the s range, no block syncs inside)
    {
        int wv = tid >> 6, lane = tid & 63;
        for (int s = wv; s <= t; s += 4){
            size_t base = ((size_t)(b*T_STEPS + s))*NN;
            float pc = 0.0f, pd = 0.0f;
            for (int k = 0; k < 16; k++){
                int i = lane + k*64;
                float r = read_w[b*NN+i];      // still old values
                pc += r * A[base+i];
                pd += r * Wf[base+i];
            }
            #pragma unroll
            for (int off = 32; off > 0; off >>= 1){
                pc += __shfl_down(pc, off);
                pd += __shfl_down(pd, off);
            }
            if (lane == 0){ cs_l[s] = pc; ds_l[s] = pd; }
        }
    }
    __syncthreads();
    // fwd/bwd with diagonal correction
    float qsum[4] = {0,0,0,0}, bw[4] = {0,0,0,0}, fw[4] = {0,0,0,0};
    for (int s = 0; s <= t; s++){
        float csv = cs_l[s], dsv = ds_l[s];
        size_t base = ((size_t)(b*T_STEPS + s))*NN;
        #pragma unroll
        for (int q = 0; q < 4; q++){
            int i = tid + q*256;
            float a = A[base+i], wv_ = Wf[base+i];
            qsum[q] += a*wv_;
            bw[q]   += dsv*a;
            fw[q]   += csv*wv_;
        }
    }
    float bwd_[4], fwd_[4];
    #pragma unroll
    for (int q = 0; q < 4; q++){
        bwd_[q] = bw[q] - ro_[q]*qsum[q];
        fwd_[q] = fw[q] - ro_[q]*qsum[q];
    }
    // prec update (reference sums w over the BATCH axis)
    #pragma unroll
    for (int q = 0; q < 4; q++){
        int i = tid + q*256;
        float wsum = wbt[0*NN+i] + wbt[1*NN+i] + wbt[2*NN+i] + wbt[3*NN+i];
        prec[b*NN+i] = (1.0f - wsum)*po_[q] + wt_[q];
    }
    // read addressing + pi mix
    {
        const float* p = rp_t + (size_t)b*RPL;
        float wcf[4];
        addr_core(cosr + b*NN, ro_, p, s4, wg, tid, wcf);
        float pr0 = p[MM+3+KSH], pr1 = p[MM+4+KSH], pr2 = p[MM+5+KSH];
        float pmx = fmaxf(pr0, fmaxf(pr1, pr2));
        float q0 = expf(pr0-pmx), q1 = expf(pr1-pmx), q2 = expf(pr2-pmx);
        float qs = q0+q1+q2;
        float pi0 = q0/qs, pi1 = q1/qs, pi2 = q2/qs;
        #pragma unroll
        for (int q = 0; q < 4; q++){
            int i = tid + q*256;
            read_w[b*NN+i] = pi0*bwd_[q] + pi1*wcf[q] + pi2*fwd_[q];
        }
    }
    // zero out region for this t (kread accumulates after)
    out_t[b*MM + tid] = 0.0f;
    // write addressing for t+1 into the other buffer
    if (do_next){
        const float* p = wp_next + (size_t)b*WPL;
        float wcf[4];
        addr_core(cosw + b*NN, wt_, p, s4, wg, tid, wcf);
        float ag = sigmoidf(p[3*MM+3+KSH]);
        #pragma unroll
        for (int q = 0; q < 4; q++){
            int i = tid + q*256;
            wbn[b*NN+i] = (1.0f-ag)*wcf[q];
        }
    }
}

// ---- reads = read_w @ memory ; 64 blocks, LDS reduce + atomicAdd ----
__global__ void kread(const float* __restrict__ mem, const float* __restrict__ read_w,
                      float* __restrict__ out_t){
    __shared__ float red[4][256];
    int tid = threadIdx.x;
    int b = blockIdx.x >> 4, nc = blockIdx.x & 15;
    int wv = tid >> 6, lane = tid & 63;
    float4 acc = make_float4(0.f, 0.f, 0.f, 0.f);
    for (int k = 0; k < 16; k++){
        int n = nc*64 + wv*16 + k;
        float r = read_w[b*NN+n];
        float4 m = ((const float4*)mem)[(size_t)(b*NN+n)*64 + lane];
        acc.x += r*m.x; acc.y += r*m.y; acc.z += r*m.z; acc.w += r*m.w;
    }
    red[wv][lane*4+0] = acc.x;
    red[wv][lane*4+1] = acc.y;
    red[wv][lane*4+2] = acc.z;
    red[wv][lane*4+3] = acc.w;
    __syncthreads();
    float v = red[0][tid] + red[1][tid] + red[2][tid] + red[3][tid];
    atomicAdd(out_t + b*MM + tid, v);
}

extern "C" void kernel_launch(void* const* d_in, const int* in_sizes, int n_in,
                              void* d_out, int out_size, void* d_ws, size_t ws_size,
                              hipStream_t stream) {
    const float* ctrl    = (const float*)d_in[0];
    const float* read_W  = (const float*)d_in[1];
    const float* read_b  = (const float*)d_in[2];
    const float* write_W = (const float*)d_in[3];
    const float* write_b = (const float*)d_in[4];
    const float* memory0 = (const float*)d_in[5];
    // d_in[6] = link0: zeros by construction (factorization assumes L0=0)
    const float* prec0   = (const float*)d_in[7];
    // d_in[8] = usage0: dead (allocation weights identically zero)
    const float* read_w0 = (const float*)d_in[9];
    const float* write_w0= (const float*)d_in[10];
    float* out = (float*)d_out;

    float* ws = (float*)d_ws;
    float* mem    = ws;                         // B*N*M = 1048576
    float* A      = mem + (size_t)BB*NN*MM;     // B*32*N = 131072
    float* Wf     = A + (size_t)BB*T_STEPS*NN;  // 131072
    float* prec   = Wf + (size_t)BB*T_STEPS*NN; // 4096
    float* read_w = prec + BB*NN;               // 4096
    float* wbuf0  = read_w + BB*NN;             // 4096
    float* wbuf1  = wbuf0 + BB*NN;              // 4096
    float* rp     = wbuf1 + BB*NN;              // 32*4*265 = 33920
    float* wp     = rp + (size_t)T_STEPS*BB*RPL;// 32*4*775 = 99200
    float* cosw   = wp + (size_t)T_STEPS*BB*WPL;// 4096
    float* cosr   = cosw + BB*NN;               // 4096

    kproj_all<<<256, 256, 0, stream>>>(ctrl, read_W, read_b, write_W, write_b, rp, wp);
    kprep<<<1024, 256, 0, stream>>>(memory0, wp, mem, cosw, prec0, read_w0, prec, read_w);
    kaddr_w0<<<BB, 256, 0, stream>>>(cosw, wp, write_w0, wbuf0);

    for (int t = 0; t < T_STEPS; t++){
        float* wbt = (t & 1) ? wbuf1 : wbuf0;
        float* wbn = (t & 1) ? wbuf0 : wbuf1;
        int tn = (t+1 < T_STEPS) ? t+1 : t;
        const float* wp_t    = wp + (size_t)t  * BB * WPL;
        const float* wp_next = wp + (size_t)tn * BB * WPL;
        const float* rp_t    = rp + (size_t)t  * BB * RPL;
        kmemcos<<<1024, 256, 0, stream>>>(mem, wbt, wp_t, rp_t, wp_next, cosr, cosw);
        kstate<<<BB, 256, 0, stream>>>(t, (t+1 < T_STEPS) ? 1 : 0,
                                       A, Wf, prec, read_w, wbt, wbn,
                                       cosr, cosw, rp_t, wp_next,
                                       out + (size_t)t*BB*MM);
        kread<<<64, 256, 0, stream>>>(mem, read_w, out + (size_t)t*BB*MM);
    }
}